// Round 13
// baseline (356.350 us; speedup 1.0000x reference)
//
#include <hip/hip_runtime.h>
#include <hip/hip_bf16.h>
#include <math.h>

#define EPS 1e-5f

static constexpr int Bb = 8;
static constexpr int Ss = 8192;
static constexpr int Dd = 1024;      // QD = KD = AD
static constexpr int NW = 64;        // pass blocks per batch (R9 value, best known)
static constexpr int NWv = NW * 4;   // wave partials per batch (256)
static constexpr int TOK = Ss / NWv; // tokens per wave (32)
static constexpr int NPAIR = TOK / 2;
static constexpr int NCH = 64;       // qk chunk count
static constexpr int RC = Dd / NCH;  // rows per chunk (16)

// ---------- helpers ----------

__device__ __forceinline__ float blk_reduce(float v, bool ismax, volatile float* lds) {
#pragma unroll
  for (int msk = 32; msk; msk >>= 1) {
    float o = __shfl_xor(v, msk);
    v = ismax ? fmaxf(v, o) : (v + o);
  }
  int w = threadIdx.x >> 6;
  __syncthreads();
  if ((threadIdx.x & 63) == 0) lds[w] = v;
  __syncthreads();
  return ismax ? fmaxf(fmaxf(lds[0], lds[1]), fmaxf(lds[2], lds[3]))
               : (lds[0] + lds[1] + lds[2] + lds[3]);
}

__device__ __forceinline__ float wred_sum(float v) {
#pragma unroll
  for (int msk = 32; msk; msk >>= 1) v += __shfl_xor(v, msk);
  return v;
}

__device__ __forceinline__ float quantf(float x, float c) {
  return fminf(fmaxf(rintf(x * c), -128.f), 127.f);
}

__device__ __forceinline__ float ternf(float w, float s) {
  return fminf(fmaxf(rintf(w / s), -1.f), 1.f);
}

__device__ __forceinline__ float4 tern4(float4 w, float s) {
  return make_float4(ternf(w.x, s), ternf(w.y, s), ternf(w.z, s), ternf(w.w, s));
}

__device__ __forceinline__ float4 quant4(float4 v, float c) {
  return make_float4(quantf(v.x, c), quantf(v.y, c), quantf(v.z, c), quantf(v.w, c));
}

__device__ __forceinline__ float absmax4(float4 v) {
  return fmaxf(fmaxf(fabsf(v.x), fabsf(v.y)), fmaxf(fabsf(v.z), fabsf(v.w)));
}

// ---------- K1: weight abs-mean scales (last-arriver finalize; proven R4/R9) ----------

__global__ __launch_bounds__(256) void k_scales(
    const float* __restrict__ w0, const float* __restrict__ w1,
    const float* __restrict__ w2, const float* __restrict__ w3,
    double* __restrict__ part, float* __restrict__ scales, int* __restrict__ cnt)
{
  int seg = blockIdx.x >> 6;
  int blk = blockIdx.x & 63;
  const float* w = seg == 0 ? w0 : seg == 1 ? w1 : seg == 2 ? w2 : w3;
  int n4 = (seg == 3 ? (1024 * 2048) : (1024 * 1024)) >> 2;
  const float4* w4 = (const float4*)w;
  double acc = 0.0;
  for (int i = blk * 256 + threadIdx.x; i < n4; i += 64 * 256) {
    float4 v = w4[i];
    acc += (double)fabsf(v.x) + (double)fabsf(v.y)
         + (double)fabsf(v.z) + (double)fabsf(v.w);
  }
  __shared__ double sred[256];
  sred[threadIdx.x] = acc;
  __syncthreads();
  for (int s = 128; s > 0; s >>= 1) {
    if (threadIdx.x < s) sred[threadIdx.x] += sred[threadIdx.x + s];
    __syncthreads();
  }
  __shared__ int lastold;
  if (threadIdx.x == 0) {
    part[blockIdx.x] = sred[0];
    __threadfence();
    lastold = atomicAdd(cnt, 1);
  }
  __syncthreads();
  if (lastold == 255) {
    __threadfence();
    if (threadIdx.x < 4) {
      int sg = threadIdx.x;
      double s = 0.0;
      for (int i = 0; i < 64; i++) s += part[sg * 64 + i];
      double n = (sg == 3) ? 2097152.0 : 1048576.0;
      scales[sg] = (float)(s / n) + EPS;
    }
  }
}

// ---------- K2: fused query quant + ternary GEMV (proven R4/R9) ----------

__global__ __launch_bounds__(256) void k_qgemv(
    const float* __restrict__ query, const float* __restrict__ W,
    const float* __restrict__ bias, const float* __restrict__ scales,
    float* __restrict__ out)
{
  __shared__ float cs[Dd];
  __shared__ float red[4];
  int b = blockIdx.x >> 8, grp = blockIdx.x & 255;
  int tid = threadIdx.x, wv = tid >> 6, lane = tid & 63;
  float4 v = ((const float4*)(query + (size_t)b * Dd))[tid];
  float am = blk_reduce(absmax4(v), true, red);
  float g = am + EPS;
  float c = 127.0f / g;
  ((float4*)cs)[tid] = quant4(v, c);
  __syncthreads();
  float s = scales[0];
  int o = grp * 4 + wv;
  const float4* wr = (const float4*)(W + (size_t)o * Dd);
  float acc = 0.f;
#pragma unroll
  for (int i = 0; i < 4; i++) {
    int idx = i * 64 + lane;
    float4 w4 = wr[idx];
    float4 a4 = ((const float4*)cs)[idx];
    acc += a4.x * ternf(w4.x, s) + a4.y * ternf(w4.y, s)
         + a4.z * ternf(w4.z, s) + a4.w * ternf(w4.w, s);
  }
  acc = wred_sum(acc);
  if (lane == 0) out[(size_t)b * Dd + o] = s * (g / 127.0f) * acc + bias[o];
}

// ---------- K3: qk with fused comb via 64-block spin (proven R4/R9) ----------

__global__ __launch_bounds__(256) void k_qk(
    const float* __restrict__ q, const float* __restrict__ Wk,
    const float* __restrict__ bk, const float* __restrict__ scales,
    float* __restrict__ part, float* __restrict__ qk, float* __restrict__ qdotbk,
    int* __restrict__ cnt)
{
  __shared__ float qs[Bb * RC];
  int ch = blockIdx.x;
  int a0 = ch * RC;
  int tid = threadIdx.x;
  if (tid < Bb * RC) {
    int b = tid / RC, a = tid - b * RC;
    qs[tid] = q[(size_t)b * Dd + a0 + a];
  }
  __syncthreads();
  float s = scales[1];
  float4 acc[Bb];
#pragma unroll
  for (int b = 0; b < Bb; b++) acc[b] = make_float4(0.f, 0.f, 0.f, 0.f);
  const float4* Wr = (const float4*)(Wk + (size_t)a0 * Dd);
  for (int i = 0; i < RC; i++) {
    float4 t4 = tern4(Wr[(size_t)i * 256 + tid], s);
#pragma unroll
    for (int b = 0; b < Bb; b++) {
      float qb = qs[b * RC + i];
      acc[b].x += qb * t4.x; acc[b].y += qb * t4.y;
      acc[b].z += qb * t4.z; acc[b].w += qb * t4.w;
    }
  }
#pragma unroll
  for (int b = 0; b < Bb; b++)
    ((float4*)part)[((size_t)ch * Bb + b) * 256 + tid] = acc[b];

  __threadfence();
  if (tid == 0) {
    atomicAdd(cnt, 1);
    while (__hip_atomic_load(cnt, __ATOMIC_ACQUIRE, __HIP_MEMORY_SCOPE_AGENT) < NCH)
      __builtin_amdgcn_s_sleep(8);
  }
  __syncthreads();
  __threadfence();

  int b = blockIdx.x >> 3, dc = blockIdx.x & 7;
  if (tid < 32) {
    int d4 = dc * 32 + tid;
    float4 a = make_float4(0.f, 0.f, 0.f, 0.f);
    for (int k = 0; k < NCH; k++) {
      float4 p = ((const float4*)part)[((size_t)k * Bb + b) * 256 + d4];
      a.x += p.x; a.y += p.y; a.z += p.z; a.w += p.w;
    }
    ((float4*)qk)[(size_t)b * 256 + d4] = make_float4(s * a.x, s * a.y, s * a.z, s * a.w);
  } else if (dc == 0 && tid >= 64 && tid < 128) {
    int lane = tid - 64;
    float p = 0.f;
    for (int a2 = lane; a2 < Dd; a2 += 64) p += q[(size_t)b * Dd + a2] * bk[a2];
    p = wred_sum(p);
    if (lane == 0) qdotbk[b] = p;
  }
}

// ---------- K4: streaming pass (R9) + DIAGNOSTIC dummy stream ----------
// Math identical to R9. After the real pass, each wave additionally streams
// its chunk of a ~768 MB cold workspace region; values folded into `sink`
// kept alive via asm (not DCE-able), never stored. This amplifies k_pass
// duration ~4x so it appears in rocprof top-5 with its achieved hbm_gbps.

__global__ __launch_bounds__(256) void k_pass(
    const float* __restrict__ X, const float* __restrict__ qk,
    const float* __restrict__ qdotbk,
    float* __restrict__ m_part, float* __restrict__ l_part,
    float* __restrict__ t_part,
    const float4* __restrict__ dummy, int dummyC4)
{
  int b    = blockIdx.x >> 6;
  int wg   = blockIdx.x & 63;
  int wv   = threadIdx.x >> 6;
  int lane = threadIdx.x & 63;
  int widx = wg * 4 + wv;
  int s0   = widx * TOK;

  const float4* qkb = (const float4*)(qk + (size_t)b * Dd);
  float4 qv0 = qkb[lane], qv1 = qkb[64 + lane], qv2 = qkb[128 + lane], qv3 = qkb[192 + lane];
  float qb = qdotbk[b];
  const float4* Xw = (const float4*)(X + ((size_t)b * Ss + s0) * Dd);

  float m = -INFINITY, l = 0.f;
  float4 a0 = make_float4(0,0,0,0), a1 = a0, a2 = a0, a3 = a0;

  float4 xA0 = Xw[lane],       xA1 = Xw[64 + lane],  xA2 = Xw[128 + lane], xA3 = Xw[192 + lane];
  float4 xB0 = Xw[256 + lane], xB1 = Xw[320 + lane], xB2 = Xw[384 + lane], xB3 = Xw[448 + lane];

  for (int p = 0; p < NPAIR; p++) {
    size_t nb = (size_t)((p + 1 < NPAIR) ? p + 1 : p) * 512;
    float4 nA0 = Xw[nb + lane],       nA1 = Xw[nb + 64 + lane],
           nA2 = Xw[nb + 128 + lane], nA3 = Xw[nb + 192 + lane];
    float4 nB0 = Xw[nb + 256 + lane], nB1 = Xw[nb + 320 + lane],
           nB2 = Xw[nb + 384 + lane], nB3 = Xw[nb + 448 + lane];

    float amA = fmaxf(fmaxf(absmax4(xA0), absmax4(xA1)), fmaxf(absmax4(xA2), absmax4(xA3)));
    float amB = fmaxf(fmaxf(absmax4(xB0), absmax4(xB1)), fmaxf(absmax4(xB2), absmax4(xB3)));
#pragma unroll
    for (int msk = 32; msk; msk >>= 1) {
      float oA = __shfl_xor(amA, msk);
      float oB = __shfl_xor(amB, msk);
      amA = fmaxf(amA, oA);
      amB = fmaxf(amB, oB);
    }
    float gA = amA + EPS, gB = amB + EPS;
    float cA = 127.0f / gA, cB = 127.0f / gB;
    float giA = gA / 127.0f, giB = gB / 127.0f;

    float qA00 = quantf(xA0.x, cA), qA01 = quantf(xA0.y, cA), qA02 = quantf(xA0.z, cA), qA03 = quantf(xA0.w, cA);
    float qA10 = quantf(xA1.x, cA), qA11 = quantf(xA1.y, cA), qA12 = quantf(xA1.z, cA), qA13 = quantf(xA1.w, cA);
    float qA20 = quantf(xA2.x, cA), qA21 = quantf(xA2.y, cA), qA22 = quantf(xA2.z, cA), qA23 = quantf(xA2.w, cA);
    float qA30 = quantf(xA3.x, cA), qA31 = quantf(xA3.y, cA), qA32 = quantf(xA3.z, cA), qA33 = quantf(xA3.w, cA);
    float qB00 = quantf(xB0.x, cB), qB01 = quantf(xB0.y, cB), qB02 = quantf(xB0.z, cB), qB03 = quantf(xB0.w, cB);
    float qB10 = quantf(xB1.x, cB), qB11 = quantf(xB1.y, cB), qB12 = quantf(xB1.z, cB), qB13 = quantf(xB1.w, cB);
    float qB20 = quantf(xB2.x, cB), qB21 = quantf(xB2.y, cB), qB22 = quantf(xB2.z, cB), qB23 = quantf(xB2.w, cB);
    float qB30 = quantf(xB3.x, cB), qB31 = quantf(xB3.y, cB), qB32 = quantf(xB3.z, cB), qB33 = quantf(xB3.w, cB);

    float dtA = qA00 * qv0.x + qA01 * qv0.y + qA02 * qv0.z + qA03 * qv0.w
              + qA10 * qv1.x + qA11 * qv1.y + qA12 * qv1.z + qA13 * qv1.w
              + qA20 * qv2.x + qA21 * qv2.y + qA22 * qv2.z + qA23 * qv2.w
              + qA30 * qv3.x + qA31 * qv3.y + qA32 * qv3.z + qA33 * qv3.w;
    float dtB = qB00 * qv0.x + qB01 * qv0.y + qB02 * qv0.z + qB03 * qv0.w
              + qB10 * qv1.x + qB11 * qv1.y + qB12 * qv1.z + qB13 * qv1.w
              + qB20 * qv2.x + qB21 * qv2.y + qB22 * qv2.z + qB23 * qv2.w
              + qB30 * qv3.x + qB31 * qv3.y + qB32 * qv3.z + qB33 * qv3.w;
#pragma unroll
    for (int msk = 32; msk; msk >>= 1) {
      float oA = __shfl_xor(dtA, msk);
      float oB = __shfl_xor(dtB, msk);
      dtA += oA;
      dtB += oB;
    }

    float sA = (dtA * giA + qb) * 0.03125f;   // / sqrt(1024)
    float sB = (dtB * giB + qb) * 0.03125f;

    float mn  = fmaxf(m, fmaxf(sA, sB));
    float scl = __expf(m - mn);               // first iter: exp(-inf)=0
    float eA  = __expf(sA - mn);
    float eB  = __expf(sB - mn);
    l = l * scl + eA + eB;
    float cfA = eA * giA, cfB = eB * giB;
    a0.x = a0.x * scl + cfA * qA00 + cfB * qB00; a0.y = a0.y * scl + cfA * qA01 + cfB * qB01;
    a0.z = a0.z * scl + cfA * qA02 + cfB * qB02; a0.w = a0.w * scl + cfA * qA03 + cfB * qB03;
    a1.x = a1.x * scl + cfA * qA10 + cfB * qB10; a1.y = a1.y * scl + cfA * qA11 + cfB * qB11;
    a1.z = a1.z * scl + cfA * qA12 + cfB * qB12; a1.w = a1.w * scl + cfA * qA13 + cfB * qB13;
    a2.x = a2.x * scl + cfA * qA20 + cfB * qB20; a2.y = a2.y * scl + cfA * qA21 + cfB * qB21;
    a2.z = a2.z * scl + cfA * qA22 + cfB * qB22; a2.w = a2.w * scl + cfA * qA23 + cfB * qB23;
    a3.x = a3.x * scl + cfA * qA30 + cfB * qB30; a3.y = a3.y * scl + cfA * qA31 + cfB * qB31;
    a3.z = a3.z * scl + cfA * qA32 + cfB * qB32; a3.w = a3.w * scl + cfA * qA33 + cfB * qB33;
    m = mn;

    xA0 = nA0; xA1 = nA1; xA2 = nA2; xA3 = nA3;
    xB0 = nB0; xB1 = nB1; xB2 = nB2; xB3 = nB3;
  }

  size_t pidx = (size_t)b * NWv + widx;
  float4* tpw = (float4*)t_part + (size_t)pidx * 256;
  tpw[lane] = a0; tpw[64 + lane] = a1; tpw[128 + lane] = a2; tpw[192 + lane] = a3;
  if (lane == 0) { m_part[pidx] = m; l_part[pidx] = l; }

  // ---- DIAGNOSTIC dummy stream (cold ws; values dead but kept alive) ----
  if (dummyC4 > 0) {
    int gw = blockIdx.x * 4 + wv;             // global wave id, 0..2047
    const float4* D = dummy + (size_t)gw * dummyC4;
    float sink = 0.f;
    for (int i = lane; i < dummyC4; i += 64) {
      float4 v = D[i];
      sink += v.x + v.y + v.z + v.w;
    }
    asm volatile("" :: "v"(sink));            // prevent DCE; never stored
  }
}

// ---------- K5: fused combine (redundant M,L; tree; last-arriver; R9) ----------

__global__ __launch_bounds__(256) void k_comb(
    const float* __restrict__ m_part, const float* __restrict__ l_part,
    const float* __restrict__ t_part, float* __restrict__ t16,
    float* __restrict__ t, int* __restrict__ cnt)
{
  __shared__ float red[4];
  int b = blockIdx.x >> 4, k = blockIdx.x & 15;
  int tid = threadIdx.x;
  float mi = m_part[(size_t)b * NWv + tid];
  float M = blk_reduce(mi, true, red);
  float li = l_part[(size_t)b * NWv + tid] * expf(mi - M);
  float L = blk_reduce(li, false, red);

  float4 acc = make_float4(0,0,0,0);
  for (int i = 0; i < 16; i++) {
    size_t pi = (size_t)b * NWv + k * 16 + i;
    float w = expf(m_part[pi] - M);
    float4 tp = ((const float4*)t_part)[pi * 256 + tid];
    acc.x += w * tp.x; acc.y += w * tp.y; acc.z += w * tp.z; acc.w += w * tp.w;
  }
  ((float4*)t16)[((size_t)(b * 16 + k)) * 256 + tid] = acc;

  __shared__ int lastold;
  if (tid == 0) {
    __threadfence();
    lastold = atomicAdd(&cnt[b], 1);
  }
  __syncthreads();
  if (lastold == 15) {
    __threadfence();
    float invL = 1.0f / L;
    float4 a = make_float4(0,0,0,0);
    for (int kk = 0; kk < 16; kk++) {
      float4 v = ((const float4*)t16)[((size_t)(b * 16 + kk)) * 256 + tid];
      a.x += v.x; a.y += v.y; a.z += v.z; a.w += v.w;
    }
    ((float4*)t)[(size_t)b * 256 + tid] =
        make_float4(a.x * invL, a.y * invL, a.z * invL, a.w * invL);
  }
}

// ---------- K6: ternary GEMV, fp32 activations (proven R4/R9) ----------

__global__ __launch_bounds__(256) void k_tern_gemv_f32(
    const float* __restrict__ act, const float* __restrict__ W,
    const float* __restrict__ bias, const float* __restrict__ scales, int sidx,
    float* __restrict__ out, int K, int N)
{
  int wave = blockIdx.x * 4 + (threadIdx.x >> 6);
  int lane = threadIdx.x & 63;
  int b = wave / N, o = wave - b * N;
  float s = scales[sidx];
  const float4* wr = (const float4*)(W + (size_t)o * K);
  const float4* ar = (const float4*)(act + (size_t)b * K);
  int n4 = K >> 2;
  float acc = 0.f;
  for (int i = lane; i < n4; i += 64) {
    float4 w4 = wr[i];
    float4 a4 = ar[i];
    acc += a4.x * ternf(w4.x, s) + a4.y * ternf(w4.y, s)
         + a4.z * ternf(w4.z, s) + a4.w * ternf(w4.w, s);
  }
  acc = wred_sum(acc);
  if (lane == 0) out[(size_t)b * N + o] = s * acc + bias[o];
}

// ---------- K7: fused [query,ctx] quant + final ternary GEMV (proven R4/R9) ----------

__global__ __launch_bounds__(256) void k_final(
    const float* __restrict__ query, const float* __restrict__ ctx,
    const float* __restrict__ W, const float* __restrict__ bias,
    const float* __restrict__ scales, float* __restrict__ out)
{
  __shared__ float cs[2 * Dd];
  __shared__ float red[4];
  int b = blockIdx.x >> 8, grp = blockIdx.x & 255;
  int tid = threadIdx.x, wv = tid >> 6, lane = tid & 63;
  float4 vq = ((const float4*)(query + (size_t)b * Dd))[tid];
  float4 vc = ((const float4*)(ctx   + (size_t)b * Dd))[tid];
  float am = blk_reduce(fmaxf(absmax4(vq), absmax4(vc)), true, red);
  float g = am + EPS;
  float c = 127.0f / g;
  ((float4*)cs)[tid]       = quant4(vq, c);
  ((float4*)cs)[256 + tid] = quant4(vc, c);
  __syncthreads();
  float s = scales[3];
  int o = grp * 4 + wv;
  const float4* wr = (const float4*)(W + (size_t)o * 2 * Dd);
  float acc = 0.f;
#pragma unroll
  for (int i = 0; i < 8; i++) {
    int idx = i * 64 + lane;
    float4 w4 = wr[idx];
    float4 a4 = ((const float4*)cs)[idx];
    acc += a4.x * ternf(w4.x, s) + a4.y * ternf(w4.y, s)
         + a4.z * ternf(w4.z, s) + a4.w * ternf(w4.w, s);
  }
  acc = wred_sum(acc);
  if (lane == 0) out[(size_t)b * Dd + o] = s * (g / 127.0f) * acc + bias[o];
}

// ---------- launch ----------

extern "C" void kernel_launch(void* const* d_in, const int* in_sizes, int n_in,
                              void* d_out, int out_size, void* d_ws, size_t ws_size,
                              hipStream_t stream)
{
  const float* query = (const float*)d_in[0];
  const float* X     = (const float*)d_in[1];
  const float* w_q   = (const float*)d_in[2];
  const float* b_q   = (const float*)d_in[3];
  const float* w_k   = (const float*)d_in[4];
  const float* b_k   = (const float*)d_in[5];
  const float* w_v   = (const float*)d_in[6];
  const float* b_v   = (const float*)d_in[7];
  const float* w_c   = (const float*)d_in[8];
  const float* b_c   = (const float*)d_in[9];
  float* out = (float*)d_out;
  char* ws = (char*)d_ws;

  size_t off = 0;
  auto alloc = [&](size_t bytes) -> size_t {
    size_t o = off;
    off += (bytes + 255) & ~(size_t)255;
    return o;
  };
  size_t o_cnt    = alloc(256);                 // [0]=scales, [1]=qk, [2..9]=comb
  size_t o_part   = alloc(256 * sizeof(double));
  size_t o_scales = alloc(4 * sizeof(float));
  size_t o_q      = alloc((size_t)Bb * Dd * 4);
  size_t o_qk     = alloc((size_t)Bb * Dd * 4);
  size_t o_qbk    = alloc(Bb * sizeof(float));
  size_t o_t      = alloc((size_t)Bb * Dd * 4);
  size_t o_ctx    = alloc((size_t)Bb * Dd * 4);
  size_t o_t16    = alloc((size_t)Bb * 16 * Dd * 4);
  size_t o_qkp    = alloc((size_t)NCH * Bb * Dd * 4);
  size_t o_mp     = alloc((size_t)Bb * NWv * 4);
  size_t o_lp     = alloc((size_t)Bb * NWv * 4);
  size_t o_tp     = alloc((size_t)Bb * NWv * Dd * 4);

  // diagnostic dummy region: up to 768 MB of leftover ws, cold-streamed by k_pass
  int dummyC4 = 0;
  size_t o_dummy = off;
  if (ws_size > off + (16u << 20)) {
    size_t avail = ws_size - off;
    size_t want  = (size_t)768 << 20;
    size_t dbytes = avail < want ? avail : want;
    size_t total4 = dbytes / 16;
    size_t per_wave = (total4 / 2048) & ~(size_t)63;  // 2048 waves in k_pass
    dummyC4 = (int)per_wave;
    o_dummy = alloc(per_wave * 2048 * 16);
  }

  int*    cnt    = (int*)(ws + o_cnt);
  double* part   = (double*)(ws + o_part);
  float*  scales = (float*)(ws + o_scales);
  float*  qv     = (float*)(ws + o_q);
  float*  qk     = (float*)(ws + o_qk);
  float*  qbk    = (float*)(ws + o_qbk);
  float*  tvec   = (float*)(ws + o_t);
  float*  ctx    = (float*)(ws + o_ctx);
  float*  t16    = (float*)(ws + o_t16);
  float*  qkp    = (float*)(ws + o_qkp);
  float*  mp     = (float*)(ws + o_mp);
  float*  lp     = (float*)(ws + o_lp);
  float*  tp     = (float*)(ws + o_tp);
  const float4* dummy = (const float4*)(ws + o_dummy);

  hipMemsetAsync(ws + o_cnt, 0, 256, stream);
  k_scales<<<256, 256, 0, stream>>>(w_q, w_k, w_v, w_c, part, scales, &cnt[0]);
  k_qgemv<<<Bb * 256, 256, 0, stream>>>(query, w_q, b_q, scales, qv);
  k_qk<<<NCH, 256, 0, stream>>>(qv, w_k, b_k, scales, qkp, qk, qbk, &cnt[1]);
  k_pass<<<Bb * NW, 256, 0, stream>>>(X, qk, qbk, mp, lp, tp, dummy, dummyC4);
  k_comb<<<Bb * 16, 256, 0, stream>>>(mp, lp, tp, t16, tvec, &cnt[2]);
  k_tern_gemv_f32<<<(Bb * Dd) / 4, 256, 0, stream>>>(tvec, w_v, b_v, scales, 2, ctx, Dd, Dd);
  k_final<<<Bb * 256, 256, 0, stream>>>(query, ctx, w_c, b_c, scales, out);
}

// Round 14
// 143.752 us; speedup vs baseline: 2.4789x; 2.4789x over previous
//
#include <hip/hip_runtime.h>
#include <hip/hip_bf16.h>
#include <math.h>

#define EPS 1e-5f

static constexpr int Bb = 8;
static constexpr int Ss = 8192;
static constexpr int Dd = 1024;      // QD = KD = AD
static constexpr int NW = 64;        // pass blocks per batch
static constexpr int NWv = NW * 4;   // wave partials per batch (256)
static constexpr int TOK = Ss / NWv; // tokens per wave (32)
static constexpr int NCH = 64;       // qk chunk count
static constexpr int RC = Dd / NCH;  // rows per chunk (16)

typedef const __attribute__((address_space(1))) void* gas_t;
typedef __attribute__((address_space(3))) void* las_t;

// ---------- helpers ----------

__device__ __forceinline__ float blk_reduce(float v, bool ismax, volatile float* lds) {
#pragma unroll
  for (int msk = 32; msk; msk >>= 1) {
    float o = __shfl_xor(v, msk);
    v = ismax ? fmaxf(v, o) : (v + o);
  }
  int w = threadIdx.x >> 6;
  __syncthreads();
  if ((threadIdx.x & 63) == 0) lds[w] = v;
  __syncthreads();
  return ismax ? fmaxf(fmaxf(lds[0], lds[1]), fmaxf(lds[2], lds[3]))
               : (lds[0] + lds[1] + lds[2] + lds[3]);
}

__device__ __forceinline__ float wred_max(float v) {
#pragma unroll
  for (int msk = 32; msk; msk >>= 1) v = fmaxf(v, __shfl_xor(v, msk));
  return v;
}

__device__ __forceinline__ float wred_sum(float v) {
#pragma unroll
  for (int msk = 32; msk; msk >>= 1) v += __shfl_xor(v, msk);
  return v;
}

__device__ __forceinline__ float quantf(float x, float c) {
  return fminf(fmaxf(rintf(x * c), -128.f), 127.f);
}

__device__ __forceinline__ float ternf(float w, float s) {
  return fminf(fmaxf(rintf(w / s), -1.f), 1.f);
}

__device__ __forceinline__ float4 tern4(float4 w, float s) {
  return make_float4(ternf(w.x, s), ternf(w.y, s), ternf(w.z, s), ternf(w.w, s));
}

__device__ __forceinline__ float4 quant4(float4 v, float c) {
  return make_float4(quantf(v.x, c), quantf(v.y, c), quantf(v.z, c), quantf(v.w, c));
}

__device__ __forceinline__ float absmax4(float4 v) {
  return fmaxf(fmaxf(fabsf(v.x), fabsf(v.y)), fmaxf(fabsf(v.z), fabsf(v.w)));
}

// ---------- K1: weight abs-mean scales (last-arriver finalize; proven R4/R9) ----------

__global__ __launch_bounds__(256) void k_scales(
    const float* __restrict__ w0, const float* __restrict__ w1,
    const float* __restrict__ w2, const float* __restrict__ w3,
    double* __restrict__ part, float* __restrict__ scales, int* __restrict__ cnt)
{
  int seg = blockIdx.x >> 6;
  int blk = blockIdx.x & 63;
  const float* w = seg == 0 ? w0 : seg == 1 ? w1 : seg == 2 ? w2 : w3;
  int n4 = (seg == 3 ? (1024 * 2048) : (1024 * 1024)) >> 2;
  const float4* w4 = (const float4*)w;
  double acc = 0.0;
  for (int i = blk * 256 + threadIdx.x; i < n4; i += 64 * 256) {
    float4 v = w4[i];
    acc += (double)fabsf(v.x) + (double)fabsf(v.y)
         + (double)fabsf(v.z) + (double)fabsf(v.w);
  }
  __shared__ double sred[256];
  sred[threadIdx.x] = acc;
  __syncthreads();
  for (int s = 128; s > 0; s >>= 1) {
    if (threadIdx.x < s) sred[threadIdx.x] += sred[threadIdx.x + s];
    __syncthreads();
  }
  __shared__ int lastold;
  if (threadIdx.x == 0) {
    part[blockIdx.x] = sred[0];
    __threadfence();
    lastold = atomicAdd(cnt, 1);
  }
  __syncthreads();
  if (lastold == 255) {
    __threadfence();
    if (threadIdx.x < 4) {
      int sg = threadIdx.x;
      double s = 0.0;
      for (int i = 0; i < 64; i++) s += part[sg * 64 + i];
      double n = (sg == 3) ? 2097152.0 : 1048576.0;
      scales[sg] = (float)(s / n) + EPS;
    }
  }
}

// ---------- K2: fused query quant + ternary GEMV (proven R4/R9) ----------

__global__ __launch_bounds__(256) void k_qgemv(
    const float* __restrict__ query, const float* __restrict__ W,
    const float* __restrict__ bias, const float* __restrict__ scales,
    float* __restrict__ out)
{
  __shared__ float cs[Dd];
  __shared__ float red[4];
  int b = blockIdx.x >> 8, grp = blockIdx.x & 255;
  int tid = threadIdx.x, wv = tid >> 6, lane = tid & 63;
  float4 v = ((const float4*)(query + (size_t)b * Dd))[tid];
  float am = blk_reduce(absmax4(v), true, red);
  float g = am + EPS;
  float c = 127.0f / g;
  ((float4*)cs)[tid] = quant4(v, c);
  __syncthreads();
  float s = scales[0];
  int o = grp * 4 + wv;
  const float4* wr = (const float4*)(W + (size_t)o * Dd);
  float acc = 0.f;
#pragma unroll
  for (int i = 0; i < 4; i++) {
    int idx = i * 64 + lane;
    float4 w4 = wr[idx];
    float4 a4 = ((const float4*)cs)[idx];
    acc += a4.x * ternf(w4.x, s) + a4.y * ternf(w4.y, s)
         + a4.z * ternf(w4.z, s) + a4.w * ternf(w4.w, s);
  }
  acc = wred_sum(acc);
  if (lane == 0) out[(size_t)b * Dd + o] = s * (g / 127.0f) * acc + bias[o];
}

// ---------- K3: qk with fused comb via 64-block spin (proven R4/R9) ----------

__global__ __launch_bounds__(256) void k_qk(
    const float* __restrict__ q, const float* __restrict__ Wk,
    const float* __restrict__ bk, const float* __restrict__ scales,
    float* __restrict__ part, float* __restrict__ qk, float* __restrict__ qdotbk,
    int* __restrict__ cnt)
{
  __shared__ float qs[Bb * RC];
  int ch = blockIdx.x;
  int a0 = ch * RC;
  int tid = threadIdx.x;
  if (tid < Bb * RC) {
    int b = tid / RC, a = tid - b * RC;
    qs[tid] = q[(size_t)b * Dd + a0 + a];
  }
  __syncthreads();
  float s = scales[1];
  float4 acc[Bb];
#pragma unroll
  for (int b = 0; b < Bb; b++) acc[b] = make_float4(0.f, 0.f, 0.f, 0.f);
  const float4* Wr = (const float4*)(Wk + (size_t)a0 * Dd);
  for (int i = 0; i < RC; i++) {
    float4 t4 = tern4(Wr[(size_t)i * 256 + tid], s);
#pragma unroll
    for (int b = 0; b < Bb; b++) {
      float qb = qs[b * RC + i];
      acc[b].x += qb * t4.x; acc[b].y += qb * t4.y;
      acc[b].z += qb * t4.z; acc[b].w += qb * t4.w;
    }
  }
#pragma unroll
  for (int b = 0; b < Bb; b++)
    ((float4*)part)[((size_t)ch * Bb + b) * 256 + tid] = acc[b];

  __threadfence();
  if (tid == 0) {
    atomicAdd(cnt, 1);
    while (__hip_atomic_load(cnt, __ATOMIC_ACQUIRE, __HIP_MEMORY_SCOPE_AGENT) < NCH)
      __builtin_amdgcn_s_sleep(8);
  }
  __syncthreads();
  __threadfence();

  int b = blockIdx.x >> 3, dc = blockIdx.x & 7;
  if (tid < 32) {
    int d4 = dc * 32 + tid;
    float4 a = make_float4(0.f, 0.f, 0.f, 0.f);
    for (int k = 0; k < NCH; k++) {
      float4 p = ((const float4*)part)[((size_t)k * Bb + b) * 256 + d4];
      a.x += p.x; a.y += p.y; a.z += p.z; a.w += p.w;
    }
    ((float4*)qk)[(size_t)b * 256 + d4] = make_float4(s * a.x, s * a.y, s * a.z, s * a.w);
  } else if (dc == 0 && tid >= 64 && tid < 128) {
    int lane = tid - 64;
    float p = 0.f;
    for (int a2 = lane; a2 < Dd; a2 += 64) p += q[(size_t)b * Dd + a2] * bk[a2];
    p = wred_sum(p);
    if (lane == 0) qdotbk[b] = p;
  }
}

// ---------- K4: streaming pass with async global->LDS staging (depth 3) ----------
// Compiler cannot sink global_load_lds (fire-and-forget DMA, no VGPR dest).
// Per wave: 4 private 4KB LDS buffers; issue token i+3 at end of iter i;
// s_waitcnt vmcnt(8) at iter start guarantees token i landed (oldest-first).

__device__ __forceinline__ void stage_tok(const float4* __restrict__ Xw,
                                          float* dst, int tok, int lane) {
#pragma unroll
  for (int j = 0; j < 4; ++j) {
    __builtin_amdgcn_global_load_lds(
        (gas_t)(Xw + (size_t)tok * 256 + j * 64 + lane),
        (las_t)(dst + j * 256),
        16, 0, 0);
  }
}

__global__ __launch_bounds__(256) void k_pass(
    const float* __restrict__ X, const float* __restrict__ qk,
    const float* __restrict__ qdotbk,
    float* __restrict__ m_part, float* __restrict__ l_part,
    float* __restrict__ t_part)
{
  __shared__ float sbuf[4][4][1024];   // [wave][buffer][token floats] = 64 KB
  int b    = blockIdx.x >> 6;
  int wg   = blockIdx.x & 63;
  int wv   = threadIdx.x >> 6;
  int lane = threadIdx.x & 63;
  int widx = wg * 4 + wv;
  int s0   = widx * TOK;

  const float4* qkb = (const float4*)(qk + (size_t)b * Dd);
  float4 qv0 = qkb[lane], qv1 = qkb[64 + lane], qv2 = qkb[128 + lane], qv3 = qkb[192 + lane];
  float qb = qdotbk[b];
  const float4* Xw = (const float4*)(X + ((size_t)b * Ss + s0) * Dd);

  // stage tokens 0..2
  stage_tok(Xw, sbuf[wv][0], 0, lane);
  stage_tok(Xw, sbuf[wv][1], 1, lane);
  stage_tok(Xw, sbuf[wv][2], 2, lane);

  float m = -INFINITY, l = 0.f;
  float4 a0 = make_float4(0,0,0,0), a1 = a0, a2 = a0, a3 = a0;

  for (int i = 0; i < TOK; i++) {
    asm volatile("s_waitcnt vmcnt(8)" ::: "memory");
    __builtin_amdgcn_sched_barrier(0);
    const float4* L = (const float4*)sbuf[wv][i & 3];
    float4 x0 = L[lane], x1 = L[64 + lane], x2 = L[128 + lane], x3 = L[192 + lane];

    float am = wred_max(fmaxf(fmaxf(absmax4(x0), absmax4(x1)),
                              fmaxf(absmax4(x2), absmax4(x3))));
    float g = am + EPS;
    float c = 127.0f / g;
    float gi = g / 127.0f;

    // clamps provably never bind: |x|*127/(rowmax+eps) < 127
    float q00 = rintf(x0.x * c), q01 = rintf(x0.y * c), q02 = rintf(x0.z * c), q03 = rintf(x0.w * c);
    float q10 = rintf(x1.x * c), q11 = rintf(x1.y * c), q12 = rintf(x1.z * c), q13 = rintf(x1.w * c);
    float q20 = rintf(x2.x * c), q21 = rintf(x2.y * c), q22 = rintf(x2.z * c), q23 = rintf(x2.w * c);
    float q30 = rintf(x3.x * c), q31 = rintf(x3.y * c), q32 = rintf(x3.z * c), q33 = rintf(x3.w * c);

    float dt = q00 * qv0.x + q01 * qv0.y + q02 * qv0.z + q03 * qv0.w
             + q10 * qv1.x + q11 * qv1.y + q12 * qv1.z + q13 * qv1.w
             + q20 * qv2.x + q21 * qv2.y + q22 * qv2.z + q23 * qv2.w
             + q30 * qv3.x + q31 * qv3.y + q32 * qv3.z + q33 * qv3.w;
    dt = wred_sum(dt);

    float score = (dt * gi + qb) * 0.03125f;   // / sqrt(1024)
    if (score <= m) {                          // wave-uniform
      float p  = __expf(score - m);
      l += p;
      float cf = p * gi;
      a0.x += cf * q00; a0.y += cf * q01; a0.z += cf * q02; a0.w += cf * q03;
      a1.x += cf * q10; a1.y += cf * q11; a1.z += cf * q12; a1.w += cf * q13;
      a2.x += cf * q20; a2.y += cf * q21; a2.z += cf * q22; a2.w += cf * q23;
      a3.x += cf * q30; a3.y += cf * q31; a3.z += cf * q32; a3.w += cf * q33;
    } else {
      float scl = __expf(m - score);
      l = l * scl + 1.0f;
      float cf = gi;
      a0.x = a0.x * scl + cf * q00; a0.y = a0.y * scl + cf * q01;
      a0.z = a0.z * scl + cf * q02; a0.w = a0.w * scl + cf * q03;
      a1.x = a1.x * scl + cf * q10; a1.y = a1.y * scl + cf * q11;
      a1.z = a1.z * scl + cf * q12; a1.w = a1.w * scl + cf * q13;
      a2.x = a2.x * scl + cf * q20; a2.y = a2.y * scl + cf * q21;
      a2.z = a2.z * scl + cf * q22; a2.w = a2.w * scl + cf * q23;
      a3.x = a3.x * scl + cf * q30; a3.y = a3.y * scl + cf * q31;
      a3.z = a3.z * scl + cf * q32; a3.w = a3.w * scl + cf * q33;
      m = score;
    }

    if (i + 3 < TOK) stage_tok(Xw, sbuf[wv][(i + 3) & 3], i + 3, lane);
  }

  size_t pidx = (size_t)b * NWv + widx;
  float4* tpw = (float4*)t_part + (size_t)pidx * 256;
  tpw[lane] = a0; tpw[64 + lane] = a1; tpw[128 + lane] = a2; tpw[192 + lane] = a3;
  if (lane == 0) { m_part[pidx] = m; l_part[pidx] = l; }
}

// ---------- K5: fused combine (redundant M,L; tree; last-arriver; R9) ----------

__global__ __launch_bounds__(256) void k_comb(
    const float* __restrict__ m_part, const float* __restrict__ l_part,
    const float* __restrict__ t_part, float* __restrict__ t16,
    float* __restrict__ t, int* __restrict__ cnt)
{
  __shared__ float red[4];
  int b = blockIdx.x >> 4, k = blockIdx.x & 15;
  int tid = threadIdx.x;
  float mi = m_part[(size_t)b * NWv + tid];
  float M = blk_reduce(mi, true, red);
  float li = l_part[(size_t)b * NWv + tid] * expf(mi - M);
  float L = blk_reduce(li, false, red);

  float4 acc = make_float4(0,0,0,0);
  for (int i = 0; i < 16; i++) {
    size_t pi = (size_t)b * NWv + k * 16 + i;
    float w = expf(m_part[pi] - M);
    float4 tp = ((const float4*)t_part)[pi * 256 + tid];
    acc.x += w * tp.x; acc.y += w * tp.y; acc.z += w * tp.z; acc.w += w * tp.w;
  }
  ((float4*)t16)[((size_t)(b * 16 + k)) * 256 + tid] = acc;

  __shared__ int lastold;
  if (tid == 0) {
    __threadfence();
    lastold = atomicAdd(&cnt[b], 1);
  }
  __syncthreads();
  if (lastold == 15) {
    __threadfence();
    float invL = 1.0f / L;
    float4 a = make_float4(0,0,0,0);
    for (int kk = 0; kk < 16; kk++) {
      float4 v = ((const float4*)t16)[((size_t)(b * 16 + kk)) * 256 + tid];
      a.x += v.x; a.y += v.y; a.z += v.z; a.w += v.w;
    }
    ((float4*)t)[(size_t)b * 256 + tid] =
        make_float4(a.x * invL, a.y * invL, a.z * invL, a.w * invL);
  }
}

// ---------- K6: ternary GEMV, fp32 activations (proven R4/R9) ----------

__global__ __launch_bounds__(256) void k_tern_gemv_f32(
    const float* __restrict__ act, const float* __restrict__ W,
    const float* __restrict__ bias, const float* __restrict__ scales, int sidx,
    float* __restrict__ out, int K, int N)
{
  int wave = blockIdx.x * 4 + (threadIdx.x >> 6);
  int lane = threadIdx.x & 63;
  int b = wave / N, o = wave - b * N;
  float s = scales[sidx];
  const float4* wr = (const float4*)(W + (size_t)o * K);
  const float4* ar = (const float4*)(act + (size_t)b * K);
  int n4 = K >> 2;
  float acc = 0.f;
  for (int i = lane; i < n4; i += 64) {
    float4 w4 = wr[i];
    float4 a4 = ar[i];
    acc += a4.x * ternf(w4.x, s) + a4.y * ternf(w4.y, s)
         + a4.z * ternf(w4.z, s) + a4.w * ternf(w4.w, s);
  }
  acc = wred_sum(acc);
  if (lane == 0) out[(size_t)b * N + o] = s * acc + bias[o];
}

// ---------- K7: fused [query,ctx] quant + final ternary GEMV (proven R4/R9) ----------

__global__ __launch_bounds__(256) void k_final(
    const float* __restrict__ query, const float* __restrict__ ctx,
    const float* __restrict__ W, const float* __restrict__ bias,
    const float* __restrict__ scales, float* __restrict__ out)
{
  __shared__ float cs[2 * Dd];
  __shared__ float red[4];
  int b = blockIdx.x >> 8, grp = blockIdx.x & 255;
  int tid = threadIdx.x, wv = tid >> 6, lane = tid & 63;
  float4 vq = ((const float4*)(query + (size_t)b * Dd))[tid];
  float4 vc = ((const float4*)(ctx   + (size_t)b * Dd))[tid];
  float am = blk_reduce(fmaxf(absmax4(vq), absmax4(vc)), true, red);
  float g = am + EPS;
  float c = 127.0f / g;
  ((float4*)cs)[tid]       = quant4(vq, c);
  ((float4*)cs)[256 + tid] = quant4(vc, c);
  __syncthreads();
  float s = scales[3];
  int o = grp * 4 + wv;
  const float4* wr = (const float4*)(W + (size_t)o * 2 * Dd);
  float acc = 0.f;
#pragma unroll
  for (int i = 0; i < 8; i++) {
    int idx = i * 64 + lane;
    float4 w4 = wr[idx];
    float4 a4 = ((const float4*)cs)[idx];
    acc += a4.x * ternf(w4.x, s) + a4.y * ternf(w4.y, s)
         + a4.z * ternf(w4.z, s) + a4.w * ternf(w4.w, s);
  }
  acc = wred_sum(acc);
  if (lane == 0) out[(size_t)b * Dd + o] = s * (g / 127.0f) * acc + bias[o];
}

// ---------- launch ----------

extern "C" void kernel_launch(void* const* d_in, const int* in_sizes, int n_in,
                              void* d_out, int out_size, void* d_ws, size_t ws_size,
                              hipStream_t stream)
{
  const float* query = (const float*)d_in[0];
  const float* X     = (const float*)d_in[1];
  const float* w_q   = (const float*)d_in[2];
  const float* b_q   = (const float*)d_in[3];
  const float* w_k   = (const float*)d_in[4];
  const float* b_k   = (const float*)d_in[5];
  const float* w_v   = (const float*)d_in[6];
  const float* b_v   = (const float*)d_in[7];
  const float* w_c   = (const float*)d_in[8];
  const float* b_c   = (const float*)d_in[9];
  float* out = (float*)d_out;
  char* ws = (char*)d_ws;

  size_t off = 0;
  auto alloc = [&](size_t bytes) -> size_t {
    size_t o = off;
    off += (bytes + 255) & ~(size_t)255;
    return o;
  };
  size_t o_cnt    = alloc(256);                 // [0]=scales, [1]=qk, [2..9]=comb
  size_t o_part   = alloc(256 * sizeof(double));
  size_t o_scales = alloc(4 * sizeof(float));
  size_t o_q      = alloc((size_t)Bb * Dd * 4);
  size_t o_qk     = alloc((size_t)Bb * Dd * 4);
  size_t o_qbk    = alloc(Bb * sizeof(float));
  size_t o_t      = alloc((size_t)Bb * Dd * 4);
  size_t o_ctx    = alloc((size_t)Bb * Dd * 4);
  size_t o_t16    = alloc((size_t)Bb * 16 * Dd * 4);
  size_t o_qkp    = alloc((size_t)NCH * Bb * Dd * 4);
  size_t o_mp     = alloc((size_t)Bb * NWv * 4);
  size_t o_lp     = alloc((size_t)Bb * NWv * 4);
  size_t o_tp     = alloc((size_t)Bb * NWv * Dd * 4);
  (void)ws_size;

  int*    cnt    = (int*)(ws + o_cnt);
  double* part   = (double*)(ws + o_part);
  float*  scales = (float*)(ws + o_scales);
  float*  qv     = (float*)(ws + o_q);
  float*  qk     = (float*)(ws + o_qk);
  float*  qbk    = (float*)(ws + o_qbk);
  float*  tvec   = (float*)(ws + o_t);
  float*  ctx    = (float*)(ws + o_ctx);
  float*  t16    = (float*)(ws + o_t16);
  float*  qkp    = (float*)(ws + o_qkp);
  float*  mp     = (float*)(ws + o_mp);
  float*  lp     = (float*)(ws + o_lp);
  float*  tp     = (float*)(ws + o_tp);

  hipMemsetAsync(ws + o_cnt, 0, 256, stream);
  k_scales<<<256, 256, 0, stream>>>(w_q, w_k, w_v, w_c, part, scales, &cnt[0]);
  k_qgemv<<<Bb * 256, 256, 0, stream>>>(query, w_q, b_q, scales, qv);
  k_qk<<<NCH, 256, 0, stream>>>(qv, w_k, b_k, scales, qkp, qk, qbk, &cnt[1]);
  k_pass<<<Bb * NW, 256, 0, stream>>>(X, qk, qbk, mp, lp, tp);
  k_comb<<<Bb * 16, 256, 0, stream>>>(mp, lp, tp, t16, tvec, &cnt[2]);
  k_tern_gemv_f32<<<(Bb * Dd) / 4, 256, 0, stream>>>(tvec, w_v, b_v, scales, 2, ctx, Dd, Dd);
  k_final<<<Bb * 256, 256, 0, stream>>>(query, ctx, w_c, b_c, scales, out);
}

// Round 15
// 122.917 us; speedup vs baseline: 2.8991x; 1.1695x over previous
//
#include <hip/hip_runtime.h>
#include <hip/hip_bf16.h>
#include <math.h>

#define EPS 1e-5f

static constexpr int Bb = 8;
static constexpr int Ss = 8192;
static constexpr int Dd = 1024;      // QD = KD = AD
static constexpr int NW = 64;        // pass blocks per batch (R9 value, best known)
static constexpr int NWv = NW * 4;   // wave partials per batch (256)
static constexpr int TOK = Ss / NWv; // tokens per wave (32)
static constexpr int NPAIR = TOK / 2;
static constexpr int NCH = 128;      // qk chunk count (was 64; 2x parallelism)
static constexpr int RC = Dd / NCH;  // rows per chunk (8)

// ---------- helpers ----------

__device__ __forceinline__ float blk_reduce(float v, bool ismax, volatile float* lds) {
#pragma unroll
  for (int msk = 32; msk; msk >>= 1) {
    float o = __shfl_xor(v, msk);
    v = ismax ? fmaxf(v, o) : (v + o);
  }
  int w = threadIdx.x >> 6;
  __syncthreads();
  if ((threadIdx.x & 63) == 0) lds[w] = v;
  __syncthreads();
  return ismax ? fmaxf(fmaxf(lds[0], lds[1]), fmaxf(lds[2], lds[3]))
               : (lds[0] + lds[1] + lds[2] + lds[3]);
}

__device__ __forceinline__ float wred_sum(float v) {
#pragma unroll
  for (int msk = 32; msk; msk >>= 1) v += __shfl_xor(v, msk);
  return v;
}

__device__ __forceinline__ float quantf(float x, float c) {
  return fminf(fmaxf(rintf(x * c), -128.f), 127.f);
}

__device__ __forceinline__ float ternf(float w, float s) {
  return fminf(fmaxf(rintf(w / s), -1.f), 1.f);
}

__device__ __forceinline__ float4 tern4(float4 w, float s) {
  return make_float4(ternf(w.x, s), ternf(w.y, s), ternf(w.z, s), ternf(w.w, s));
}

__device__ __forceinline__ float4 quant4(float4 v, float c) {
  return make_float4(quantf(v.x, c), quantf(v.y, c), quantf(v.z, c), quantf(v.w, c));
}

__device__ __forceinline__ float absmax4(float4 v) {
  return fmaxf(fmaxf(fabsf(v.x), fabsf(v.y)), fmaxf(fabsf(v.z), fabsf(v.w)));
}

// ---------- K1: weight abs-mean scales (last-arriver finalize; proven R4/R9) ----------

__global__ __launch_bounds__(256) void k_scales(
    const float* __restrict__ w0, const float* __restrict__ w1,
    const float* __restrict__ w2, const float* __restrict__ w3,
    double* __restrict__ part, float* __restrict__ scales, int* __restrict__ cnt)
{
  int seg = blockIdx.x >> 6;
  int blk = blockIdx.x & 63;
  const float* w = seg == 0 ? w0 : seg == 1 ? w1 : seg == 2 ? w2 : w3;
  int n4 = (seg == 3 ? (1024 * 2048) : (1024 * 1024)) >> 2;
  const float4* w4 = (const float4*)w;
  double acc = 0.0;
  for (int i = blk * 256 + threadIdx.x; i < n4; i += 64 * 256) {
    float4 v = w4[i];
    acc += (double)fabsf(v.x) + (double)fabsf(v.y)
         + (double)fabsf(v.z) + (double)fabsf(v.w);
  }
  __shared__ double sred[256];
  sred[threadIdx.x] = acc;
  __syncthreads();
  for (int s = 128; s > 0; s >>= 1) {
    if (threadIdx.x < s) sred[threadIdx.x] += sred[threadIdx.x + s];
    __syncthreads();
  }
  __shared__ int lastold;
  if (threadIdx.x == 0) {
    part[blockIdx.x] = sred[0];
    __threadfence();
    lastold = atomicAdd(cnt, 1);
  }
  __syncthreads();
  if (lastold == 255) {
    __threadfence();
    if (threadIdx.x < 4) {
      int sg = threadIdx.x;
      double s = 0.0;
      for (int i = 0; i < 64; i++) s += part[sg * 64 + i];
      double n = (sg == 3) ? 2097152.0 : 1048576.0;
      scales[sg] = (float)(s / n) + EPS;
    }
  }
}

// ---------- K2: fused query quant + ternary GEMV (proven R4/R9) ----------

__global__ __launch_bounds__(256) void k_qgemv(
    const float* __restrict__ query, const float* __restrict__ W,
    const float* __restrict__ bias, const float* __restrict__ scales,
    float* __restrict__ out)
{
  __shared__ float cs[Dd];
  __shared__ float red[4];
  int b = blockIdx.x >> 8, grp = blockIdx.x & 255;
  int tid = threadIdx.x, wv = tid >> 6, lane = tid & 63;
  float4 v = ((const float4*)(query + (size_t)b * Dd))[tid];
  float am = blk_reduce(absmax4(v), true, red);
  float g = am + EPS;
  float c = 127.0f / g;
  ((float4*)cs)[tid] = quant4(v, c);
  __syncthreads();
  float s = scales[0];
  int o = grp * 4 + wv;
  const float4* wr = (const float4*)(W + (size_t)o * Dd);
  float acc = 0.f;
#pragma unroll
  for (int i = 0; i < 4; i++) {
    int idx = i * 64 + lane;
    float4 w4 = wr[idx];
    float4 a4 = ((const float4*)cs)[idx];
    acc += a4.x * ternf(w4.x, s) + a4.y * ternf(w4.y, s)
         + a4.z * ternf(w4.z, s) + a4.w * ternf(w4.w, s);
  }
  acc = wred_sum(acc);
  if (lane == 0) out[(size_t)b * Dd + o] = s * (g / 127.0f) * acc + bias[o];
}

// ---------- K3a: qk chunk partials (128 blocks, RC=8, no spin) ----------

__global__ __launch_bounds__(256) void k_qk_part(
    const float* __restrict__ q, const float* __restrict__ Wk,
    const float* __restrict__ scales, float* __restrict__ part)
{
  __shared__ float qs2[Bb * RC];   // 64 floats
  int ch = blockIdx.x, a0 = ch * RC;
  int tid = threadIdx.x;
  if (tid < Bb * RC) {
    int b = tid >> 3, a = tid & 7;   // RC = 8
    qs2[tid] = q[(size_t)b * Dd + a0 + a];
  }
  __syncthreads();
  float s = scales[1];
  float4 acc[Bb];
#pragma unroll
  for (int b = 0; b < Bb; b++) acc[b] = make_float4(0.f, 0.f, 0.f, 0.f);
  const float4* Wr = (const float4*)(Wk + (size_t)a0 * Dd);
#pragma unroll
  for (int i = 0; i < RC; i++) {
    float4 t4 = tern4(Wr[(size_t)i * 256 + tid], s);
#pragma unroll
    for (int b = 0; b < Bb; b++) {
      float qb = qs2[b * RC + i];
      acc[b].x += qb * t4.x; acc[b].y += qb * t4.y;
      acc[b].z += qb * t4.z; acc[b].w += qb * t4.w;
    }
  }
#pragma unroll
  for (int b = 0; b < Bb; b++)
    ((float4*)part)[((size_t)ch * Bb + b) * 256 + tid] = acc[b];
}

// ---------- K3b: qk combine (128 blocks, all 256 threads) + q.b_k ----------
// block (b, g): columns d4 = g*16 + c (c=tid&15); kg = tid>>4 sums 8 chunks.

__global__ __launch_bounds__(256) void k_qk_comb(
    const float* __restrict__ part, const float* __restrict__ q,
    const float* __restrict__ bk, const float* __restrict__ scales,
    float* __restrict__ qk, float* __restrict__ qdotbk)
{
  __shared__ float4 lred[16][17];
  int b = blockIdx.x >> 4, g = blockIdx.x & 15;
  int tid = threadIdx.x;
  int c = tid & 15, kg = tid >> 4;
  int d4 = g * 16 + c;
  float s = scales[1];
  float4 a = make_float4(0.f, 0.f, 0.f, 0.f);
#pragma unroll
  for (int j = 0; j < NCH / 16; j++) {         // 8 iterations
    int ch = kg * (NCH / 16) + j;
    float4 p = ((const float4*)part)[((size_t)ch * Bb + b) * 256 + d4];
    a.x += p.x; a.y += p.y; a.z += p.z; a.w += p.w;
  }
  lred[kg][c] = a;
  __syncthreads();
  if (kg == 0) {
    float4 t = lred[0][c];
#pragma unroll
    for (int k = 1; k < 16; k++) {
      float4 v = lred[k][c];
      t.x += v.x; t.y += v.y; t.z += v.z; t.w += v.w;
    }
    ((float4*)qk)[(size_t)b * 256 + d4] =
        make_float4(s * t.x, s * t.y, s * t.z, s * t.w);
  } else if (g == 0 && tid >= 64 && tid < 128) {
    int lane = tid - 64;
    float p = 0.f;
    for (int a2 = lane; a2 < Dd; a2 += 64) p += q[(size_t)b * Dd + a2] * bk[a2];
    p = wred_sum(p);
    if (lane == 0) qdotbk[b] = p;
  }
}

// ---------- K4: streaming pass; TWO tokens/iter, interleaved chains (R9, best) ----------

__global__ __launch_bounds__(256) void k_pass(
    const float* __restrict__ X, const float* __restrict__ qk,
    const float* __restrict__ qdotbk,
    float* __restrict__ m_part, float* __restrict__ l_part,
    float* __restrict__ t_part)
{
  int b    = blockIdx.x >> 6;
  int wg   = blockIdx.x & 63;
  int wv   = threadIdx.x >> 6;
  int lane = threadIdx.x & 63;
  int widx = wg * 4 + wv;
  int s0   = widx * TOK;

  const float4* qkb = (const float4*)(qk + (size_t)b * Dd);
  float4 qv0 = qkb[lane], qv1 = qkb[64 + lane], qv2 = qkb[128 + lane], qv3 = qkb[192 + lane];
  float qb = qdotbk[b];
  const float4* Xw = (const float4*)(X + ((size_t)b * Ss + s0) * Dd);

  float m = -INFINITY, l = 0.f;
  float4 a0 = make_float4(0,0,0,0), a1 = a0, a2 = a0, a3 = a0;

  float4 xA0 = Xw[lane],       xA1 = Xw[64 + lane],  xA2 = Xw[128 + lane], xA3 = Xw[192 + lane];
  float4 xB0 = Xw[256 + lane], xB1 = Xw[320 + lane], xB2 = Xw[384 + lane], xB3 = Xw[448 + lane];

  for (int p = 0; p < NPAIR; p++) {
    size_t nb = (size_t)((p + 1 < NPAIR) ? p + 1 : p) * 512;
    float4 nA0 = Xw[nb + lane],       nA1 = Xw[nb + 64 + lane],
           nA2 = Xw[nb + 128 + lane], nA3 = Xw[nb + 192 + lane];
    float4 nB0 = Xw[nb + 256 + lane], nB1 = Xw[nb + 320 + lane],
           nB2 = Xw[nb + 384 + lane], nB3 = Xw[nb + 448 + lane];

    float amA = fmaxf(fmaxf(absmax4(xA0), absmax4(xA1)), fmaxf(absmax4(xA2), absmax4(xA3)));
    float amB = fmaxf(fmaxf(absmax4(xB0), absmax4(xB1)), fmaxf(absmax4(xB2), absmax4(xB3)));
#pragma unroll
    for (int msk = 32; msk; msk >>= 1) {
      float oA = __shfl_xor(amA, msk);
      float oB = __shfl_xor(amB, msk);
      amA = fmaxf(amA, oA);
      amB = fmaxf(amB, oB);
    }
    float gA = amA + EPS, gB = amB + EPS;
    float cA = 127.0f / gA, cB = 127.0f / gB;
    float giA = gA / 127.0f, giB = gB / 127.0f;

    float qA00 = quantf(xA0.x, cA), qA01 = quantf(xA0.y, cA), qA02 = quantf(xA0.z, cA), qA03 = quantf(xA0.w, cA);
    float qA10 = quantf(xA1.x, cA), qA11 = quantf(xA1.y, cA), qA12 = quantf(xA1.z, cA), qA13 = quantf(xA1.w, cA);
    float qA20 = quantf(xA2.x, cA), qA21 = quantf(xA2.y, cA), qA22 = quantf(xA2.z, cA), qA23 = quantf(xA2.w, cA);
    float qA30 = quantf(xA3.x, cA), qA31 = quantf(xA3.y, cA), qA32 = quantf(xA3.z, cA), qA33 = quantf(xA3.w, cA);
    float qB00 = quantf(xB0.x, cB), qB01 = quantf(xB0.y, cB), qB02 = quantf(xB0.z, cB), qB03 = quantf(xB0.w, cB);
    float qB10 = quantf(xB1.x, cB), qB11 = quantf(xB1.y, cB), qB12 = quantf(xB1.z, cB), qB13 = quantf(xB1.w, cB);
    float qB20 = quantf(xB2.x, cB), qB21 = quantf(xB2.y, cB), qB22 = quantf(xB2.z, cB), qB23 = quantf(xB2.w, cB);
    float qB30 = quantf(xB3.x, cB), qB31 = quantf(xB3.y, cB), qB32 = quantf(xB3.z, cB), qB33 = quantf(xB3.w, cB);

    float dtA = qA00 * qv0.x + qA01 * qv0.y + qA02 * qv0.z + qA03 * qv0.w
              + qA10 * qv1.x + qA11 * qv1.y + qA12 * qv1.z + qA13 * qv1.w
              + qA20 * qv2.x + qA21 * qv2.y + qA22 * qv2.z + qA23 * qv2.w
              + qA30 * qv3.x + qA31 * qv3.y + qA32 * qv3.z + qA33 * qv3.w;
    float dtB = qB00 * qv0.x + qB01 * qv0.y + qB02 * qv0.z + qB03 * qv0.w
              + qB10 * qv1.x + qB11 * qv1.y + qB12 * qv1.z + qB13 * qv1.w
              + qB20 * qv2.x + qB21 * qv2.y + qB22 * qv2.z + qB23 * qv2.w
              + qB30 * qv3.x + qB31 * qv3.y + qB32 * qv3.z + qB33 * qv3.w;
#pragma unroll
    for (int msk = 32; msk; msk >>= 1) {
      float oA = __shfl_xor(dtA, msk);
      float oB = __shfl_xor(dtB, msk);
      dtA += oA;
      dtB += oB;
    }

    float sA = (dtA * giA + qb) * 0.03125f;   // / sqrt(1024)
    float sB = (dtB * giB + qb) * 0.03125f;

    float mn  = fmaxf(m, fmaxf(sA, sB));
    float scl = __expf(m - mn);               // first iter: exp(-inf)=0
    float eA  = __expf(sA - mn);
    float eB  = __expf(sB - mn);
    l = l * scl + eA + eB;
    float cfA = eA * giA, cfB = eB * giB;
    a0.x = a0.x * scl + cfA * qA00 + cfB * qB00; a0.y = a0.y * scl + cfA * qA01 + cfB * qB01;
    a0.z = a0.z * scl + cfA * qA02 + cfB * qB02; a0.w = a0.w * scl + cfA * qA03 + cfB * qB03;
    a1.x = a1.x * scl + cfA * qA10 + cfB * qB10; a1.y = a1.y * scl + cfA * qA11 + cfB * qB11;
    a1.z = a1.z * scl + cfA * qA12 + cfB * qB12; a1.w = a1.w * scl + cfA * qA13 + cfB * qB13;
    a2.x = a2.x * scl + cfA * qA20 + cfB * qB20; a2.y = a2.y * scl + cfA * qA21 + cfB * qB21;
    a2.z = a2.z * scl + cfA * qA22 + cfB * qB22; a2.w = a2.w * scl + cfA * qA23 + cfB * qB23;
    a3.x = a3.x * scl + cfA * qA30 + cfB * qB30; a3.y = a3.y * scl + cfA * qA31 + cfB * qB31;
    a3.z = a3.z * scl + cfA * qA32 + cfB * qB32; a3.w = a3.w * scl + cfA * qA33 + cfB * qB33;
    m = mn;

    xA0 = nA0; xA1 = nA1; xA2 = nA2; xA3 = nA3;
    xB0 = nB0; xB1 = nB1; xB2 = nB2; xB3 = nB3;
  }

  size_t pidx = (size_t)b * NWv + widx;
  float4* tpw = (float4*)t_part + (size_t)pidx * 256;
  tpw[lane] = a0; tpw[64 + lane] = a1; tpw[128 + lane] = a2; tpw[192 + lane] = a3;
  if (lane == 0) { m_part[pidx] = m; l_part[pidx] = l; }
}

// ---------- K5: fused combine (redundant M,L; tree; last-arriver per batch; R9) ----------

__global__ __launch_bounds__(256) void k_comb(
    const float* __restrict__ m_part, const float* __restrict__ l_part,
    const float* __restrict__ t_part, float* __restrict__ t16,
    float* __restrict__ t, int* __restrict__ cnt)
{
  __shared__ float red[4];
  int b = blockIdx.x >> 4, k = blockIdx.x & 15;
  int tid = threadIdx.x;
  float mi = m_part[(size_t)b * NWv + tid];
  float M = blk_reduce(mi, true, red);
  float li = l_part[(size_t)b * NWv + tid] * expf(mi - M);
  float L = blk_reduce(li, false, red);

  float4 acc = make_float4(0,0,0,0);
  for (int i = 0; i < 16; i++) {
    size_t pi = (size_t)b * NWv + k * 16 + i;
    float w = expf(m_part[pi] - M);
    float4 tp = ((const float4*)t_part)[pi * 256 + tid];
    acc.x += w * tp.x; acc.y += w * tp.y; acc.z += w * tp.z; acc.w += w * tp.w;
  }
  ((float4*)t16)[((size_t)(b * 16 + k)) * 256 + tid] = acc;

  __shared__ int lastold;
  if (tid == 0) {
    __threadfence();
    lastold = atomicAdd(&cnt[b], 1);
  }
  __syncthreads();
  if (lastold == 15) {
    __threadfence();
    float invL = 1.0f / L;
    float4 a = make_float4(0,0,0,0);
    for (int kk = 0; kk < 16; kk++) {
      float4 v = ((const float4*)t16)[((size_t)(b * 16 + kk)) * 256 + tid];
      a.x += v.x; a.y += v.y; a.z += v.z; a.w += v.w;
    }
    ((float4*)t)[(size_t)b * 256 + tid] =
        make_float4(a.x * invL, a.y * invL, a.z * invL, a.w * invL);
  }
}

// ---------- K6: ternary GEMV, fp32 activations (proven R4/R9) ----------

__global__ __launch_bounds__(256) void k_tern_gemv_f32(
    const float* __restrict__ act, const float* __restrict__ W,
    const float* __restrict__ bias, const float* __restrict__ scales, int sidx,
    float* __restrict__ out, int K, int N)
{
  int wave = blockIdx.x * 4 + (threadIdx.x >> 6);
  int lane = threadIdx.x & 63;
  int b = wave / N, o = wave - b * N;
  float s = scales[sidx];
  const float4* wr = (const float4*)(W + (size_t)o * K);
  const float4* ar = (const float4*)(act + (size_t)b * K);
  int n4 = K >> 2;
  float acc = 0.f;
  for (int i = lane; i < n4; i += 64) {
    float4 w4 = wr[i];
    float4 a4 = ar[i];
    acc += a4.x * ternf(w4.x, s) + a4.y * ternf(w4.y, s)
         + a4.z * ternf(w4.z, s) + a4.w * ternf(w4.w, s);
  }
  acc = wred_sum(acc);
  if (lane == 0) out[(size_t)b * N + o] = s * acc + bias[o];
}

// ---------- K7: fused [query,ctx] quant + final ternary GEMV (proven R4/R9) ----------

__global__ __launch_bounds__(256) void k_final(
    const float* __restrict__ query, const float* __restrict__ ctx,
    const float* __restrict__ W, const float* __restrict__ bias,
    const float* __restrict__ scales, float* __restrict__ out)
{
  __shared__ float cs[2 * Dd];
  __shared__ float red[4];
  int b = blockIdx.x >> 8, grp = blockIdx.x & 255;
  int tid = threadIdx.x, wv = tid >> 6, lane = tid & 63;
  float4 vq = ((const float4*)(query + (size_t)b * Dd))[tid];
  float4 vc = ((const float4*)(ctx   + (size_t)b * Dd))[tid];
  float am = blk_reduce(fmaxf(absmax4(vq), absmax4(vc)), true, red);
  float g = am + EPS;
  float c = 127.0f / g;
  ((float4*)cs)[tid]       = quant4(vq, c);
  ((float4*)cs)[256 + tid] = quant4(vc, c);
  __syncthreads();
  float s = scales[3];
  int o = grp * 4 + wv;
  const float4* wr = (const float4*)(W + (size_t)o * 2 * Dd);
  float acc = 0.f;
#pragma unroll
  for (int i = 0; i < 8; i++) {
    int idx = i * 64 + lane;
    float4 w4 = wr[idx];
    float4 a4 = ((const float4*)cs)[idx];
    acc += a4.x * ternf(w4.x, s) + a4.y * ternf(w4.y, s)
         + a4.z * ternf(w4.z, s) + a4.w * ternf(w4.w, s);
  }
  acc = wred_sum(acc);
  if (lane == 0) out[(size_t)b * Dd + o] = s * (g / 127.0f) * acc + bias[o];
}

// ---------- launch ----------

extern "C" void kernel_launch(void* const* d_in, const int* in_sizes, int n_in,
                              void* d_out, int out_size, void* d_ws, size_t ws_size,
                              hipStream_t stream)
{
  const float* query = (const float*)d_in[0];
  const float* X     = (const float*)d_in[1];
  const float* w_q   = (const float*)d_in[2];
  const float* b_q   = (const float*)d_in[3];
  const float* w_k   = (const float*)d_in[4];
  const float* b_k   = (const float*)d_in[5];
  const float* w_v   = (const float*)d_in[6];
  const float* b_v   = (const float*)d_in[7];
  const float* w_c   = (const float*)d_in[8];
  const float* b_c   = (const float*)d_in[9];
  float* out = (float*)d_out;
  char* ws = (char*)d_ws;

  size_t off = 0;
  auto alloc = [&](size_t bytes) -> size_t {
    size_t o = off;
    off += (bytes + 255) & ~(size_t)255;
    return o;
  };
  size_t o_cnt    = alloc(256);                 // [0]=scales, [2..9]=comb
  size_t o_part   = alloc(256 * sizeof(double));
  size_t o_scales = alloc(4 * sizeof(float));
  size_t o_q      = alloc((size_t)Bb * Dd * 4);
  size_t o_qk     = alloc((size_t)Bb * Dd * 4);
  size_t o_qbk    = alloc(Bb * sizeof(float));
  size_t o_t      = alloc((size_t)Bb * Dd * 4);
  size_t o_ctx    = alloc((size_t)Bb * Dd * 4);
  size_t o_t16    = alloc((size_t)Bb * 16 * Dd * 4);
  size_t o_qkp    = alloc((size_t)NCH * Bb * Dd * 4);
  size_t o_mp     = alloc((size_t)Bb * NWv * 4);
  size_t o_lp     = alloc((size_t)Bb * NWv * 4);
  size_t o_tp     = alloc((size_t)Bb * NWv * Dd * 4);
  (void)ws_size;

  int*    cnt    = (int*)(ws + o_cnt);
  double* part   = (double*)(ws + o_part);
  float*  scales = (float*)(ws + o_scales);
  float*  qv     = (float*)(ws + o_q);
  float*  qk     = (float*)(ws + o_qk);
  float*  qbk    = (float*)(ws + o_qbk);
  float*  tvec   = (float*)(ws + o_t);
  float*  ctx    = (float*)(ws + o_ctx);
  float*  t16    = (float*)(ws + o_t16);
  float*  qkp    = (float*)(ws + o_qkp);
  float*  mp     = (float*)(ws + o_mp);
  float*  lp     = (float*)(ws + o_lp);
  float*  tp     = (float*)(ws + o_tp);

  hipMemsetAsync(ws + o_cnt, 0, 256, stream);
  k_scales<<<256, 256, 0, stream>>>(w_q, w_k, w_v, w_c, part, scales, &cnt[0]);
  k_qgemv<<<Bb * 256, 256, 0, stream>>>(query, w_q, b_q, scales, qv);
  k_qk_part<<<NCH, 256, 0, stream>>>(qv, w_k, scales, qkp);
  k_qk_comb<<<Bb * 16, 256, 0, stream>>>(qkp, qv, b_k, scales, qk, qbk);
  k_pass<<<Bb * NW, 256, 0, stream>>>(X, qk, qbk, mp, lp, tp);
  k_comb<<<Bb * 16, 256, 0, stream>>>(mp, lp, tp, t16, tvec, &cnt[2]);
  k_tern_gemv_f32<<<(Bb * Dd) / 4, 256, 0, stream>>>(tvec, w_v, b_v, scales, 2, ctx, Dd, Dd);
  k_final<<<Bb * 256, 256, 0, stream>>>(query, ctx, w_c, b_c, scales, out);
}

// Round 16
// 120.079 us; speedup vs baseline: 2.9676x; 1.0236x over previous
//
#include <hip/hip_runtime.h>
#include <hip/hip_bf16.h>
#include <math.h>

#define EPS 1e-5f

static constexpr int Bb = 8;
static constexpr int Ss = 8192;
static constexpr int Dd = 1024;      // QD = KD = AD
static constexpr int NW = 64;        // pass blocks per batch
static constexpr int NWv = NW * 4;   // waves per batch (256)
static constexpr int TOK = Ss / NWv; // tokens per wave (32)
static constexpr int NPAIR = TOK / 2;
static constexpr int NCH = 128;      // qk chunk count
static constexpr int RC = Dd / NCH;  // rows per chunk (8)

// ---------- helpers ----------

__device__ __forceinline__ float blk_reduce(float v, bool ismax, volatile float* lds) {
#pragma unroll
  for (int msk = 32; msk; msk >>= 1) {
    float o = __shfl_xor(v, msk);
    v = ismax ? fmaxf(v, o) : (v + o);
  }
  int w = threadIdx.x >> 6;
  __syncthreads();
  if ((threadIdx.x & 63) == 0) lds[w] = v;
  __syncthreads();
  return ismax ? fmaxf(fmaxf(lds[0], lds[1]), fmaxf(lds[2], lds[3]))
               : (lds[0] + lds[1] + lds[2] + lds[3]);
}

__device__ __forceinline__ float wred_sum(float v) {
#pragma unroll
  for (int msk = 32; msk; msk >>= 1) v += __shfl_xor(v, msk);
  return v;
}

__device__ __forceinline__ float quantf(float x, float c) {
  return fminf(fmaxf(rintf(x * c), -128.f), 127.f);
}

__device__ __forceinline__ float ternf(float w, float s) {
  return fminf(fmaxf(rintf(w / s), -1.f), 1.f);
}

__device__ __forceinline__ float4 tern4(float4 w, float s) {
  return make_float4(ternf(w.x, s), ternf(w.y, s), ternf(w.z, s), ternf(w.w, s));
}

__device__ __forceinline__ float4 quant4(float4 v, float c) {
  return make_float4(quantf(v.x, c), quantf(v.y, c), quantf(v.z, c), quantf(v.w, c));
}

__device__ __forceinline__ float absmax4(float4 v) {
  return fmaxf(fmaxf(fabsf(v.x), fabsf(v.y)), fmaxf(fabsf(v.z), fabsf(v.w)));
}

// ---------- K1: weight abs-mean scales (last-arriver finalize; proven R4/R9) ----------

__global__ __launch_bounds__(256) void k_scales(
    const float* __restrict__ w0, const float* __restrict__ w1,
    const float* __restrict__ w2, const float* __restrict__ w3,
    double* __restrict__ part, float* __restrict__ scales, int* __restrict__ cnt)
{
  int seg = blockIdx.x >> 6;
  int blk = blockIdx.x & 63;
  const float* w = seg == 0 ? w0 : seg == 1 ? w1 : seg == 2 ? w2 : w3;
  int n4 = (seg == 3 ? (1024 * 2048) : (1024 * 1024)) >> 2;
  const float4* w4 = (const float4*)w;
  double acc = 0.0;
  for (int i = blk * 256 + threadIdx.x; i < n4; i += 64 * 256) {
    float4 v = w4[i];
    acc += (double)fabsf(v.x) + (double)fabsf(v.y)
         + (double)fabsf(v.z) + (double)fabsf(v.w);
  }
  __shared__ double sred[256];
  sred[threadIdx.x] = acc;
  __syncthreads();
  for (int s = 128; s > 0; s >>= 1) {
    if (threadIdx.x < s) sred[threadIdx.x] += sred[threadIdx.x + s];
    __syncthreads();
  }
  __shared__ int lastold;
  if (threadIdx.x == 0) {
    part[blockIdx.x] = sred[0];
    __threadfence();
    lastold = atomicAdd(cnt, 1);
  }
  __syncthreads();
  if (lastold == 255) {
    __threadfence();
    if (threadIdx.x < 4) {
      int sg = threadIdx.x;
      double s = 0.0;
      for (int i = 0; i < 64; i++) s += part[sg * 64 + i];
      double n = (sg == 3) ? 2097152.0 : 1048576.0;
      scales[sg] = (float)(s / n) + EPS;
    }
  }
}

// ---------- K2: fused query quant + ternary GEMV (proven R4/R9) ----------

__global__ __launch_bounds__(256) void k_qgemv(
    const float* __restrict__ query, const float* __restrict__ W,
    const float* __restrict__ bias, const float* __restrict__ scales,
    float* __restrict__ out)
{
  __shared__ float cs[Dd];
  __shared__ float red[4];
  int b = blockIdx.x >> 8, grp = blockIdx.x & 255;
  int tid = threadIdx.x, wv = tid >> 6, lane = tid & 63;
  float4 v = ((const float4*)(query + (size_t)b * Dd))[tid];
  float am = blk_reduce(absmax4(v), true, red);
  float g = am + EPS;
  float c = 127.0f / g;
  ((float4*)cs)[tid] = quant4(v, c);
  __syncthreads();
  float s = scales[0];
  int o = grp * 4 + wv;
  const float4* wr = (const float4*)(W + (size_t)o * Dd);
  float acc = 0.f;
#pragma unroll
  for (int i = 0; i < 4; i++) {
    int idx = i * 64 + lane;
    float4 w4 = wr[idx];
    float4 a4 = ((const float4*)cs)[idx];
    acc += a4.x * ternf(w4.x, s) + a4.y * ternf(w4.y, s)
         + a4.z * ternf(w4.z, s) + a4.w * ternf(w4.w, s);
  }
  acc = wred_sum(acc);
  if (lane == 0) out[(size_t)b * Dd + o] = s * (g / 127.0f) * acc + bias[o];
}

// ---------- K3a: qk chunk partials (128 blocks, RC=8, no spin; R15) ----------

__global__ __launch_bounds__(256) void k_qk_part(
    const float* __restrict__ q, const float* __restrict__ Wk,
    const float* __restrict__ scales, float* __restrict__ part)
{
  __shared__ float qs2[Bb * RC];   // 64 floats
  int ch = blockIdx.x, a0 = ch * RC;
  int tid = threadIdx.x;
  if (tid < Bb * RC) {
    int b = tid >> 3, a = tid & 7;   // RC = 8
    qs2[tid] = q[(size_t)b * Dd + a0 + a];
  }
  __syncthreads();
  float s = scales[1];
  float4 acc[Bb];
#pragma unroll
  for (int b = 0; b < Bb; b++) acc[b] = make_float4(0.f, 0.f, 0.f, 0.f);
  const float4* Wr = (const float4*)(Wk + (size_t)a0 * Dd);
#pragma unroll
  for (int i = 0; i < RC; i++) {
    float4 t4 = tern4(Wr[(size_t)i * 256 + tid], s);
#pragma unroll
    for (int b = 0; b < Bb; b++) {
      float qb = qs2[b * RC + i];
      acc[b].x += qb * t4.x; acc[b].y += qb * t4.y;
      acc[b].z += qb * t4.z; acc[b].w += qb * t4.w;
    }
  }
#pragma unroll
  for (int b = 0; b < Bb; b++)
    ((float4*)part)[((size_t)ch * Bb + b) * 256 + tid] = acc[b];
}

// ---------- K3b: qk combine (128 blocks, all 256 threads) + q.b_k (R15) ----------

__global__ __launch_bounds__(256) void k_qk_comb(
    const float* __restrict__ part, const float* __restrict__ q,
    const float* __restrict__ bk, const float* __restrict__ scales,
    float* __restrict__ qk, float* __restrict__ qdotbk)
{
  __shared__ float4 lred[16][17];
  int b = blockIdx.x >> 4, g = blockIdx.x & 15;
  int tid = threadIdx.x;
  int c = tid & 15, kg = tid >> 4;
  int d4 = g * 16 + c;
  float s = scales[1];
  float4 a = make_float4(0.f, 0.f, 0.f, 0.f);
#pragma unroll
  for (int j = 0; j < NCH / 16; j++) {
    int ch = kg * (NCH / 16) + j;
    float4 p = ((const float4*)part)[((size_t)ch * Bb + b) * 256 + d4];
    a.x += p.x; a.y += p.y; a.z += p.z; a.w += p.w;
  }
  lred[kg][c] = a;
  __syncthreads();
  if (kg == 0) {
    float4 t = lred[0][c];
#pragma unroll
    for (int k = 1; k < 16; k++) {
      float4 v = lred[k][c];
      t.x += v.x; t.y += v.y; t.z += v.z; t.w += v.w;
    }
    ((float4*)qk)[(size_t)b * 256 + d4] =
        make_float4(s * t.x, s * t.y, s * t.z, s * t.w);
  } else if (g == 0 && tid >= 64 && tid < 128) {
    int lane = tid - 64;
    float p = 0.f;
    for (int a2 = lane; a2 < Dd; a2 += 64) p += q[(size_t)b * Dd + a2] * bk[a2];
    p = wred_sum(p);
    if (lane == 0) qdotbk[b] = p;
  }
}

// ---------- K4: streaming pass; INTERLEAVED token ownership ----------
// Wave widx owns tokens widx + k*NWv (k=0..TOK-1): at any instant the 256
// waves of a batch sweep ONE contiguous ~1MB window through X (DRAM-friendly),
// instead of 2048 scattered private streams. Math order-invariant (online max).

__global__ __launch_bounds__(256) void k_pass(
    const float* __restrict__ X, const float* __restrict__ qk,
    const float* __restrict__ qdotbk,
    float* __restrict__ m_part, float* __restrict__ l_part,
    float* __restrict__ t_part)
{
  int b    = blockIdx.x >> 6;
  int wg   = blockIdx.x & 63;
  int wv   = threadIdx.x >> 6;
  int lane = threadIdx.x & 63;
  int widx = wg * 4 + wv;

  const float4* qkb = (const float4*)(qk + (size_t)b * Dd);
  float4 qv0 = qkb[lane], qv1 = qkb[64 + lane], qv2 = qkb[128 + lane], qv3 = qkb[192 + lane];
  float qb = qdotbk[b];
  const float4* Xb = (const float4*)(X + (size_t)b * Ss * Dd);

  // token slot k -> float4 base offset
  auto tokoff = [&](int k) -> size_t {
    return (size_t)(widx + k * NWv) * 256;
  };

  float m = -INFINITY, l = 0.f;
  float4 a0 = make_float4(0,0,0,0), a1 = a0, a2 = a0, a3 = a0;

  size_t oA = tokoff(0), oB = tokoff(1);
  float4 xA0 = Xb[oA + lane], xA1 = Xb[oA + 64 + lane], xA2 = Xb[oA + 128 + lane], xA3 = Xb[oA + 192 + lane];
  float4 xB0 = Xb[oB + lane], xB1 = Xb[oB + 64 + lane], xB2 = Xb[oB + 128 + lane], xB3 = Xb[oB + 192 + lane];

  for (int p = 0; p < NPAIR; p++) {
    int kn = (p + 1 < NPAIR) ? 2 * p + 2 : 2 * p;
    size_t nA = tokoff(kn), nB = tokoff(kn + 1);
    float4 nA0 = Xb[nA + lane], nA1 = Xb[nA + 64 + lane],
           nA2 = Xb[nA + 128 + lane], nA3 = Xb[nA + 192 + lane];
    float4 nB0 = Xb[nB + lane], nB1 = Xb[nB + 64 + lane],
           nB2 = Xb[nB + 128 + lane], nB3 = Xb[nB + 192 + lane];

    float amA = fmaxf(fmaxf(absmax4(xA0), absmax4(xA1)), fmaxf(absmax4(xA2), absmax4(xA3)));
    float amB = fmaxf(fmaxf(absmax4(xB0), absmax4(xB1)), fmaxf(absmax4(xB2), absmax4(xB3)));
#pragma unroll
    for (int msk = 32; msk; msk >>= 1) {
      float oAm = __shfl_xor(amA, msk);
      float oBm = __shfl_xor(amB, msk);
      amA = fmaxf(amA, oAm);
      amB = fmaxf(amB, oBm);
    }
    float gA = amA + EPS, gB = amB + EPS;
    float cA = 127.0f / gA, cB = 127.0f / gB;
    float giA = gA / 127.0f, giB = gB / 127.0f;

    float qA00 = quantf(xA0.x, cA), qA01 = quantf(xA0.y, cA), qA02 = quantf(xA0.z, cA), qA03 = quantf(xA0.w, cA);
    float qA10 = quantf(xA1.x, cA), qA11 = quantf(xA1.y, cA), qA12 = quantf(xA1.z, cA), qA13 = quantf(xA1.w, cA);
    float qA20 = quantf(xA2.x, cA), qA21 = quantf(xA2.y, cA), qA22 = quantf(xA2.z, cA), qA23 = quantf(xA2.w, cA);
    float qA30 = quantf(xA3.x, cA), qA31 = quantf(xA3.y, cA), qA32 = quantf(xA3.z, cA), qA33 = quantf(xA3.w, cA);
    float qB00 = quantf(xB0.x, cB), qB01 = quantf(xB0.y, cB), qB02 = quantf(xB0.z, cB), qB03 = quantf(xB0.w, cB);
    float qB10 = quantf(xB1.x, cB), qB11 = quantf(xB1.y, cB), qB12 = quantf(xB1.z, cB), qB13 = quantf(xB1.w, cB);
    float qB20 = quantf(xB2.x, cB), qB21 = quantf(xB2.y, cB), qB22 = quantf(xB2.z, cB), qB23 = quantf(xB2.w, cB);
    float qB30 = quantf(xB3.x, cB), qB31 = quantf(xB3.y, cB), qB32 = quantf(xB3.z, cB), qB33 = quantf(xB3.w, cB);

    float dtA = qA00 * qv0.x + qA01 * qv0.y + qA02 * qv0.z + qA03 * qv0.w
              + qA10 * qv1.x + qA11 * qv1.y + qA12 * qv1.z + qA13 * qv1.w
              + qA20 * qv2.x + qA21 * qv2.y + qA22 * qv2.z + qA23 * qv2.w
              + qA30 * qv3.x + qA31 * qv3.y + qA32 * qv3.z + qA33 * qv3.w;
    float dtB = qB00 * qv0.x + qB01 * qv0.y + qB02 * qv0.z + qB03 * qv0.w
              + qB10 * qv1.x + qB11 * qv1.y + qB12 * qv1.z + qB13 * qv1.w
              + qB20 * qv2.x + qB21 * qv2.y + qB22 * qv2.z + qB23 * qv2.w
              + qB30 * qv3.x + qB31 * qv3.y + qB32 * qv3.z + qB33 * qv3.w;
#pragma unroll
    for (int msk = 32; msk; msk >>= 1) {
      float oAd = __shfl_xor(dtA, msk);
      float oBd = __shfl_xor(dtB, msk);
      dtA += oAd;
      dtB += oBd;
    }

    float sA = (dtA * giA + qb) * 0.03125f;   // / sqrt(1024)
    float sB = (dtB * giB + qb) * 0.03125f;

    float mn  = fmaxf(m, fmaxf(sA, sB));
    float scl = __expf(m - mn);               // first iter: exp(-inf)=0
    float eA  = __expf(sA - mn);
    float eB  = __expf(sB - mn);
    l = l * scl + eA + eB;
    float cfA = eA * giA, cfB = eB * giB;
    a0.x = a0.x * scl + cfA * qA00 + cfB * qB00; a0.y = a0.y * scl + cfA * qA01 + cfB * qB01;
    a0.z = a0.z * scl + cfA * qA02 + cfB * qB02; a0.w = a0.w * scl + cfA * qA03 + cfB * qB03;
    a1.x = a1.x * scl + cfA * qA10 + cfB * qB10; a1.y = a1.y * scl + cfA * qA11 + cfB * qB11;
    a1.z = a1.z * scl + cfA * qA12 + cfB * qB12; a1.w = a1.w * scl + cfA * qA13 + cfB * qB13;
    a2.x = a2.x * scl + cfA * qA20 + cfB * qB20; a2.y = a2.y * scl + cfA * qA21 + cfB * qB21;
    a2.z = a2.z * scl + cfA * qA22 + cfB * qB22; a2.w = a2.w * scl + cfA * qA23 + cfB * qB23;
    a3.x = a3.x * scl + cfA * qA30 + cfB * qB30; a3.y = a3.y * scl + cfA * qA31 + cfB * qB31;
    a3.z = a3.z * scl + cfA * qA32 + cfB * qB32; a3.w = a3.w * scl + cfA * qA33 + cfB * qB33;
    m = mn;

    xA0 = nA0; xA1 = nA1; xA2 = nA2; xA3 = nA3;
    xB0 = nB0; xB1 = nB1; xB2 = nB2; xB3 = nB3;
  }

  size_t pidx = (size_t)b * NWv + widx;
  float4* tpw = (float4*)t_part + (size_t)pidx * 256;
  tpw[lane] = a0; tpw[64 + lane] = a1; tpw[128 + lane] = a2; tpw[192 + lane] = a3;
  if (lane == 0) { m_part[pidx] = m; l_part[pidx] = l; }
}

// ---------- K5: fused combine (redundant M,L; tree; last-arriver per batch; R9) ----------

__global__ __launch_bounds__(256) void k_comb(
    const float* __restrict__ m_part, const float* __restrict__ l_part,
    const float* __restrict__ t_part, float* __restrict__ t16,
    float* __restrict__ t, int* __restrict__ cnt)
{
  __shared__ float red[4];
  int b = blockIdx.x >> 4, k = blockIdx.x & 15;
  int tid = threadIdx.x;
  float mi = m_part[(size_t)b * NWv + tid];
  float M = blk_reduce(mi, true, red);
  float li = l_part[(size_t)b * NWv + tid] * expf(mi - M);
  float L = blk_reduce(li, false, red);

  float4 acc = make_float4(0,0,0,0);
  for (int i = 0; i < 16; i++) {
    size_t pi = (size_t)b * NWv + k * 16 + i;
    float w = expf(m_part[pi] - M);
    float4 tp = ((const float4*)t_part)[pi * 256 + tid];
    acc.x += w * tp.x; acc.y += w * tp.y; acc.z += w * tp.z; acc.w += w * tp.w;
  }
  ((float4*)t16)[((size_t)(b * 16 + k)) * 256 + tid] = acc;

  __shared__ int lastold;
  if (tid == 0) {
    __threadfence();
    lastold = atomicAdd(&cnt[b], 1);
  }
  __syncthreads();
  if (lastold == 15) {
    __threadfence();
    float invL = 1.0f / L;
    float4 a = make_float4(0,0,0,0);
    for (int kk = 0; kk < 16; kk++) {
      float4 v = ((const float4*)t16)[((size_t)(b * 16 + kk)) * 256 + tid];
      a.x += v.x; a.y += v.y; a.z += v.z; a.w += v.w;
    }
    ((float4*)t)[(size_t)b * 256 + tid] =
        make_float4(a.x * invL, a.y * invL, a.z * invL, a.w * invL);
  }
}

// ---------- K6: ternary GEMV, fp32 activations (proven R4/R9) ----------

__global__ __launch_bounds__(256) void k_tern_gemv_f32(
    const float* __restrict__ act, const float* __restrict__ W,
    const float* __restrict__ bias, const float* __restrict__ scales, int sidx,
    float* __restrict__ out, int K, int N)
{
  int wave = blockIdx.x * 4 + (threadIdx.x >> 6);
  int lane = threadIdx.x & 63;
  int b = wave / N, o = wave - b * N;
  float s = scales[sidx];
  const float4* wr = (const float4*)(W + (size_t)o * K);
  const float4* ar = (const float4*)(act + (size_t)b * K);
  int n4 = K >> 2;
  float acc = 0.f;
  for (int i = lane; i < n4; i += 64) {
    float4 w4 = wr[i];
    float4 a4 = ar[i];
    acc += a4.x * ternf(w4.x, s) + a4.y * ternf(w4.y, s)
         + a4.z * ternf(w4.z, s) + a4.w * ternf(w4.w, s);
  }
  acc = wred_sum(acc);
  if (lane == 0) out[(size_t)b * N + o] = s * acc + bias[o];
}

// ---------- K7: fused [query,ctx] quant + final ternary GEMV (proven R4/R9) ----------

__global__ __launch_bounds__(256) void k_final(
    const float* __restrict__ query, const float* __restrict__ ctx,
    const float* __restrict__ W, const float* __restrict__ bias,
    const float* __restrict__ scales, float* __restrict__ out)
{
  __shared__ float cs[2 * Dd];
  __shared__ float red[4];
  int b = blockIdx.x >> 8, grp = blockIdx.x & 255;
  int tid = threadIdx.x, wv = tid >> 6, lane = tid & 63;
  float4 vq = ((const float4*)(query + (size_t)b * Dd))[tid];
  float4 vc = ((const float4*)(ctx   + (size_t)b * Dd))[tid];
  float am = blk_reduce(fmaxf(absmax4(vq), absmax4(vc)), true, red);
  float g = am + EPS;
  float c = 127.0f / g;
  ((float4*)cs)[tid]       = quant4(vq, c);
  ((float4*)cs)[256 + tid] = quant4(vc, c);
  __syncthreads();
  float s = scales[3];
  int o = grp * 4 + wv;
  const float4* wr = (const float4*)(W + (size_t)o * 2 * Dd);
  float acc = 0.f;
#pragma unroll
  for (int i = 0; i < 8; i++) {
    int idx = i * 64 + lane;
    float4 w4 = wr[idx];
    float4 a4 = ((const float4*)cs)[idx];
    acc += a4.x * ternf(w4.x, s) + a4.y * ternf(w4.y, s)
         + a4.z * ternf(w4.z, s) + a4.w * ternf(w4.w, s);
  }
  acc = wred_sum(acc);
  if (lane == 0) out[(size_t)b * Dd + o] = s * (g / 127.0f) * acc + bias[o];
}

// ---------- launch ----------

extern "C" void kernel_launch(void* const* d_in, const int* in_sizes, int n_in,
                              void* d_out, int out_size, void* d_ws, size_t ws_size,
                              hipStream_t stream)
{
  const float* query = (const float*)d_in[0];
  const float* X     = (const float*)d_in[1];
  const float* w_q   = (const float*)d_in[2];
  const float* b_q   = (const float*)d_in[3];
  const float* w_k   = (const float*)d_in[4];
  const float* b_k   = (const float*)d_in[5];
  const float* w_v   = (const float*)d_in[6];
  const float* b_v   = (const float*)d_in[7];
  const float* w_c   = (const float*)d_in[8];
  const float* b_c   = (const float*)d_in[9];
  float* out = (float*)d_out;
  char* ws = (char*)d_ws;

  size_t off = 0;
  auto alloc = [&](size_t bytes) -> size_t {
    size_t o = off;
    off += (bytes + 255) & ~(size_t)255;
    return o;
  };
  size_t o_cnt    = alloc(256);                 // [0]=scales, [2..9]=comb
  size_t o_part   = alloc(256 * sizeof(double));
  size_t o_scales = alloc(4 * sizeof(float));
  size_t o_q      = alloc((size_t)Bb * Dd * 4);
  size_t o_qk     = alloc((size_t)Bb * Dd * 4);
  size_t o_qbk    = alloc(Bb * sizeof(float));
  size_t o_t      = alloc((size_t)Bb * Dd * 4);
  size_t o_ctx    = alloc((size_t)Bb * Dd * 4);
  size_t o_t16    = alloc((size_t)Bb * 16 * Dd * 4);
  size_t o_qkp    = alloc((size_t)NCH * Bb * Dd * 4);
  size_t o_mp     = alloc((size_t)Bb * NWv * 4);
  size_t o_lp     = alloc((size_t)Bb * NWv * 4);
  size_t o_tp     = alloc((size_t)Bb * NWv * Dd * 4);
  (void)ws_size;

  int*    cnt    = (int*)(ws + o_cnt);
  double* part   = (double*)(ws + o_part);
  float*  scales = (float*)(ws + o_scales);
  float*  qv     = (float*)(ws + o_q);
  float*  qk     = (float*)(ws + o_qk);
  float*  qbk    = (float*)(ws + o_qbk);
  float*  tvec   = (float*)(ws + o_t);
  float*  ctx    = (float*)(ws + o_ctx);
  float*  t16    = (float*)(ws + o_t16);
  float*  qkp    = (float*)(ws + o_qkp);
  float*  mp     = (float*)(ws + o_mp);
  float*  lp     = (float*)(ws + o_lp);
  float*  tp     = (float*)(ws + o_tp);

  hipMemsetAsync(ws + o_cnt, 0, 256, stream);
  k_scales<<<256, 256, 0, stream>>>(w_q, w_k, w_v, w_c, part, scales, &cnt[0]);
  k_qgemv<<<Bb * 256, 256, 0, stream>>>(query, w_q, b_q, scales, qv);
  k_qk_part<<<NCH, 256, 0, stream>>>(qv, w_k, scales, qkp);
  k_qk_comb<<<Bb * 16, 256, 0, stream>>>(qkp, qv, b_k, scales, qk, qbk);
  k_pass<<<Bb * NW, 256, 0, stream>>>(X, qk, qbk, mp, lp, tp);
  k_comb<<<Bb * 16, 256, 0, stream>>>(mp, lp, tp, t16, tvec, &cnt[2]);
  k_tern_gemv_f32<<<(Bb * Dd) / 4, 256, 0, stream>>>(tvec, w_v, b_v, scales, 2, ctx, Dd, Dd);
  k_final<<<Bb * 256, 256, 0, stream>>>(query, ctx, w_c, b_c, scales, out);
}